// Round 1
// baseline (133.061 us; speedup 1.0000x reference)
//
#include <hip/hip_runtime.h>
#include <math.h>

// FutureEncoder: B=4, S=2048, D=1024, FUTURE_K=32, fp32 in/out.
// One wave per token, online softmax over the 32 future rows.

constexpr int KF = 32;
constexpr int S_CONST = 2048;
constexpr int D_CONST = 1024;

__global__ __launch_bounds__(256, 4)
void future_encoder_kernel(const float* __restrict__ h,
                           float* __restrict__ out,
                           int ntok) {
    const int wid  = (blockIdx.x * blockDim.x + threadIdx.x) >> 6;  // wave id = token id
    const int lane = threadIdx.x & 63;
    if (wid >= ntok) return;

    const int s = wid & (S_CONST - 1);          // position within sequence
    const size_t base = (size_t)wid * D_CONST;
    const int doff = lane * 4;                  // lane's float4 offset within each 256-chunk

    const float* qrow = h + base + doff;
    // query: 4 interleaved float4 chunks (dims c*256 + lane*4 .. +3) -> fully coalesced
    float4 q0 = *(const float4*)(qrow + 0 * 256);
    float4 q1 = *(const float4*)(qrow + 1 * 256);
    float4 q2 = *(const float4*)(qrow + 2 * 256);
    float4 q3 = *(const float4*)(qrow + 3 * 256);

    float4 a0 = {0.f, 0.f, 0.f, 0.f};
    float4 a1 = {0.f, 0.f, 0.f, 0.f};
    float4 a2 = {0.f, 0.f, 0.f, 0.f};
    float4 a3 = {0.f, 0.f, 0.f, 0.f};
    float m = -1e30f;   // running max
    float l = 0.f;      // running denom

    const int kmax = min(KF, S_CONST - 1 - s);  // number of valid future positions
    const float* frow = qrow + D_CONST;         // row s+1, lane-offset applied

    #pragma unroll 2
    for (int k = 0; k < kmax; ++k, frow += D_CONST) {
        float4 f0 = *(const float4*)(frow + 0 * 256);
        float4 f1 = *(const float4*)(frow + 1 * 256);
        float4 f2 = *(const float4*)(frow + 2 * 256);
        float4 f3 = *(const float4*)(frow + 3 * 256);

        // partial dot over this lane's 16 dims
        float p;
        p  = q0.x * f0.x + q0.y * f0.y + q0.z * f0.z + q0.w * f0.w;
        p += q1.x * f1.x + q1.y * f1.y + q1.z * f1.z + q1.w * f1.w;
        p += q2.x * f2.x + q2.y * f2.y + q2.z * f2.z + q2.w * f2.w;
        p += q3.x * f3.x + q3.y * f3.y + q3.z * f3.z + q3.w * f3.w;

        // 64-lane butterfly reduce -> every lane holds the full score
        #pragma unroll
        for (int i = 1; i < 64; i <<= 1) p += __shfl_xor(p, i, 64);

        // online softmax update
        float nm    = fmaxf(m, p);
        float scale = __expf(m - nm);   // m=-1e30 first iter -> exp(-huge)=0
        float e     = __expf(p - nm);
        m = nm;
        l = l * scale + e;

        a0.x = a0.x * scale + e * f0.x;  a0.y = a0.y * scale + e * f0.y;
        a0.z = a0.z * scale + e * f0.z;  a0.w = a0.w * scale + e * f0.w;
        a1.x = a1.x * scale + e * f1.x;  a1.y = a1.y * scale + e * f1.y;
        a1.z = a1.z * scale + e * f1.z;  a1.w = a1.w * scale + e * f1.w;
        a2.x = a2.x * scale + e * f2.x;  a2.y = a2.y * scale + e * f2.y;
        a2.z = a2.z * scale + e * f2.z;  a2.w = a2.w * scale + e * f2.w;
        a3.x = a3.x * scale + e * f3.x;  a3.y = a3.y * scale + e * f3.y;
        a3.z = a3.z * scale + e * f3.z;  a3.w = a3.w * scale + e * f3.w;
    }

    const float inv = (kmax > 0) ? (1.0f / l) : 0.0f;   // s==S-1 -> zeros

    float* orow = out + base + doff;
    float4 r0 = {a0.x * inv, a0.y * inv, a0.z * inv, a0.w * inv};
    float4 r1 = {a1.x * inv, a1.y * inv, a1.z * inv, a1.w * inv};
    float4 r2 = {a2.x * inv, a2.y * inv, a2.z * inv, a2.w * inv};
    float4 r3 = {a3.x * inv, a3.y * inv, a3.z * inv, a3.w * inv};
    *(float4*)(orow + 0 * 256) = r0;
    *(float4*)(orow + 1 * 256) = r1;
    *(float4*)(orow + 2 * 256) = r2;
    *(float4*)(orow + 3 * 256) = r3;
}

extern "C" void kernel_launch(void* const* d_in, const int* in_sizes, int n_in,
                              void* d_out, int out_size, void* d_ws, size_t ws_size,
                              hipStream_t stream) {
    const float* h = (const float*)d_in[0];
    float* out = (float*)d_out;
    const int ntok = in_sizes[0] / D_CONST;          // B*S = 8192
    const int blocks = (ntok + 3) / 4;               // 4 waves (tokens) per 256-thread block
    future_encoder_kernel<<<blocks, 256, 0, stream>>>(h, out, ntok);
}

// Round 2
// 114.026 us; speedup vs baseline: 1.1669x; 1.1669x over previous
//
#include <hip/hip_runtime.h>
#include <math.h>

// FutureEncoder: B=4, S=2048, D=1024, FUTURE_K=32, fp32 in/out.
// R2: XCD-aware block swizzle (contiguous token chunk per XCD) +
//     2 tokens per wave sharing the overlapping future-row loads.

constexpr int KF = 32;
constexpr int S_CONST = 2048;
constexpr int D_CONST = 1024;

__device__ inline float dot16(const float4* q, const float4* f) {
    float p = 0.f;
    #pragma unroll
    for (int c = 0; c < 4; ++c)
        p += q[c].x * f[c].x + q[c].y * f[c].y + q[c].z * f[c].z + q[c].w * f[c].w;
    return p;
}

__device__ inline float allreduce64(float p) {
    #pragma unroll
    for (int i = 1; i < 64; i <<= 1) p += __shfl_xor(p, i, 64);
    return p;
}

// online-softmax update of one token's accumulator with row f, score p
__device__ inline void upd(float4* a, float& m, float& l, float p, const float4* f) {
    float nm = fmaxf(m, p);
    float sc = __expf(m - nm);      // first iter: exp(-huge) = 0
    float e  = __expf(p - nm);
    m = nm;
    l = l * sc + e;
    #pragma unroll
    for (int c = 0; c < 4; ++c) {
        a[c].x = a[c].x * sc + e * f[c].x;
        a[c].y = a[c].y * sc + e * f[c].y;
        a[c].z = a[c].z * sc + e * f[c].z;
        a[c].w = a[c].w * sc + e * f[c].w;
    }
}

__global__ __launch_bounds__(256, 4)
void future_encoder_kernel(const float* __restrict__ h,
                           float* __restrict__ out,
                           int ntok) {
    // XCD swizzle: HW maps blockIdx round-robin over 8 XCDs (blk % 8).
    // Remap so each XCD handles a CONTIGUOUS chunk of blocks -> per-XCD
    // working set ~4 MiB = its L2, instead of the whole input.
    int bid  = blockIdx.x;
    int nblk = gridDim.x;
    int lb   = bid;
    if ((nblk & 7) == 0) {
        int per = nblk >> 3;
        lb = (bid & 7) * per + (bid >> 3);
    }

    const int wave = threadIdx.x >> 6;
    const int lane = threadIdx.x & 63;
    const int pid  = lb * 4 + wave;      // pair id: tokens 2*pid, 2*pid+1
    const int t0   = pid * 2;
    if (t0 >= ntok) return;

    const int s0 = t0 & (S_CONST - 1);   // even; pairs never straddle sequences
    const size_t base0 = (size_t)t0 * D_CONST + lane * 4;
    const float* r0p = h + base0;

    float4 q0[4], q1[4];
    #pragma unroll
    for (int c = 0; c < 4; ++c) q0[c] = *(const float4*)(r0p + c * 256);
    #pragma unroll
    for (int c = 0; c < 4; ++c) q1[c] = *(const float4*)(r0p + D_CONST + c * 256);

    float4 a0[4] = {}, a1[4] = {};
    float m0 = -1e30f, l0 = 0.f, m1 = -1e30f, l1 = 0.f;

    // rows t0+1 .. t0+jmax exist within this sequence (jmax >= 1 since s0<=2046)
    const int jmax = min(33, (S_CONST - 1) - s0);

    // j = 1: row t0+1 == q1's own row -> no load needed; token0 only
    {
        float p0 = allreduce64(dot16(q0, q1));
        upd(a0, m0, l0, p0, q1);
    }

    // j = 2 .. min(32, jmax): both tokens use this row (k0=j, k1=j-1)
    const int j2 = min(KF, jmax);
    const float* fp = r0p + 2 * D_CONST;
    #pragma unroll 2
    for (int j = 2; j <= j2; ++j, fp += D_CONST) {
        float4 f[4];
        #pragma unroll
        for (int c = 0; c < 4; ++c) f[c] = *(const float4*)(fp + c * 256);
        float p0 = dot16(q0, f);
        float p1 = dot16(q1, f);
        #pragma unroll
        for (int i = 1; i < 64; i <<= 1) {      // two interleaved butterflies (ILP)
            p0 += __shfl_xor(p0, i, 64);
            p1 += __shfl_xor(p1, i, 64);
        }
        upd(a0, m0, l0, p0, f);
        upd(a1, m1, l1, p1, f);
    }

    // j = 33: token1's k=32 row only
    if (jmax >= 33) {
        float4 f[4];
        #pragma unroll
        for (int c = 0; c < 4; ++c) f[c] = *(const float4*)(fp + c * 256);
        float p1 = allreduce64(dot16(q1, f));
        upd(a1, m1, l1, p1, f);
    }

    const float inv0 = 1.0f / l0;                        // token0 always has >=1 valid row
    const float inv1 = (jmax >= 2) ? (1.0f / l1) : 0.f;  // token1 empty only when s0==2046

    float* o0 = out + base0;
    #pragma unroll
    for (int c = 0; c < 4; ++c) {
        float4 r = {a0[c].x * inv0, a0[c].y * inv0, a0[c].z * inv0, a0[c].w * inv0};
        *(float4*)(o0 + c * 256) = r;
    }
    #pragma unroll
    for (int c = 0; c < 4; ++c) {
        float4 r = {a1[c].x * inv1, a1[c].y * inv1, a1[c].z * inv1, a1[c].w * inv1};
        *(float4*)(o0 + D_CONST + c * 256) = r;
    }
}

extern "C" void kernel_launch(void* const* d_in, const int* in_sizes, int n_in,
                              void* d_out, int out_size, void* d_ws, size_t ws_size,
                              hipStream_t stream) {
    const float* h = (const float*)d_in[0];
    float* out = (float*)d_out;
    const int ntok  = in_sizes[0] / D_CONST;   // B*S = 8192
    const int pairs = (ntok + 1) / 2;          // 4096
    const int blocks = (pairs + 3) / 4;        // 4 waves (pairs) per 256-thread block
    future_encoder_kernel<<<blocks, 256, 0, stream>>>(h, out, ntok);
}

// Round 3
// 105.419 us; speedup vs baseline: 1.2622x; 1.0816x over previous
//
#include <hip/hip_runtime.h>
#include <math.h>

// FutureEncoder: B=4, S=2048, D=1024, FUTURE_K=32, fp32 in/out.
// R3: MFMA (split-bf16, 3-product) banded scores + LDS softmax + fp32 VALU PV.
// Block = 16 tokens, 4 waves. Waves split D (256 each) for scores,
// split tokens (4 each) for PV. XCD-contiguous block swizzle.

constexpr int S_CONST = 2048;
constexpr int D = 1024;
constexpr int G = 16;            // tokens per block
constexpr int NTOK = 8192;
constexpr int JW = 48;           // score columns per group (band width 16+32)
constexpr int JP = 49;           // padded stride

typedef short bf16x8 __attribute__((ext_vector_type(8)));
typedef float f32x4  __attribute__((ext_vector_type(4)));

__device__ inline unsigned short f2bf(float x) {       // fp32 -> bf16 RNE
    unsigned u = __builtin_bit_cast(unsigned, x);
    u += 0x7fffu + ((u >> 16) & 1u);
    return (unsigned short)(u >> 16);
}
__device__ inline float bf2f(unsigned short h) {
    unsigned u = ((unsigned)h) << 16;
    return __builtin_bit_cast(float, u);
}

// 8 fp32 -> hi/lo bf16 fragments (split so hi+lo ~ exact)
__device__ inline void cvt8(float4 x0, float4 x1, bf16x8& hi, bf16x8& lo) {
    float xs[8] = {x0.x, x0.y, x0.z, x0.w, x1.x, x1.y, x1.z, x1.w};
    #pragma unroll
    for (int e = 0; e < 8; ++e) {
        unsigned short h = f2bf(xs[e]);
        float hf = bf2f(h);
        unsigned short l = f2bf(xs[e] - hf);
        hi[e] = (short)h;
        lo[e] = (short)l;
    }
}

__global__ __launch_bounds__(256, 2)
void future_encoder_kernel(const float* __restrict__ h,
                           float* __restrict__ out) {
    __shared__ float sc[4 * G * JP];   // per-wave partial scores [w][m][j]
    __shared__ float wm[G * JP];       // final softmax weights  [i][j]

    // XCD swizzle: contiguous 64-block chunk per XCD (512 blocks / 8 XCDs)
    int bid = blockIdx.x, nblk = gridDim.x, lb = bid;
    if ((nblk & 7) == 0) {
        int per = nblk >> 3;
        lb = (bid & 7) * per + (bid >> 3);
    }

    const int tid  = threadIdx.x;
    const int w    = tid >> 6;
    const int lane = tid & 63;
    const int t0   = lb * G;                    // first token of group
    const int s0   = t0 & (S_CONST - 1);        // groups never straddle sequences
    const int jlim = (S_CONST - 2) - s0;        // max valid j (>= 14 always)

    // ---------------- Phase 1: scores via MFMA, wave w owns D-slice ----------
    {
        const int d0   = w * 256;
        const int mrow = lane & 15;             // fragment row (token / f-row)
        const int q8   = (lane >> 4) * 8;       // k-chunk within K=32 step

        const float* ap = h + (size_t)(t0 + mrow) * D + d0 + q8;
        const float* bp0; const float* bp1; const float* bp2;
        {
            int r0 = min(t0 + 1 +  0 + mrow, NTOK - 1);
            int r1 = min(t0 + 1 + 16 + mrow, NTOK - 1);
            int r2 = min(t0 + 1 + 32 + mrow, NTOK - 1);
            bp0 = h + (size_t)r0 * D + d0 + q8;
            bp1 = h + (size_t)r1 * D + d0 + q8;
            bp2 = h + (size_t)r2 * D + d0 + q8;
        }

        f32x4 acc[3] = {{0,0,0,0},{0,0,0,0},{0,0,0,0}};

        #pragma unroll
        for (int kk = 0; kk < 8; ++kk) {
            const int o = kk * 32;
            bf16x8 ah, al;
            cvt8(*(const float4*)(ap + o), *(const float4*)(ap + o + 4), ah, al);

            bf16x8 bh, bl;
            cvt8(*(const float4*)(bp0 + o), *(const float4*)(bp0 + o + 4), bh, bl);
            acc[0] = __builtin_amdgcn_mfma_f32_16x16x32_bf16(ah, bh, acc[0], 0, 0, 0);
            acc[0] = __builtin_amdgcn_mfma_f32_16x16x32_bf16(ah, bl, acc[0], 0, 0, 0);
            acc[0] = __builtin_amdgcn_mfma_f32_16x16x32_bf16(al, bh, acc[0], 0, 0, 0);

            cvt8(*(const float4*)(bp1 + o), *(const float4*)(bp1 + o + 4), bh, bl);
            acc[1] = __builtin_amdgcn_mfma_f32_16x16x32_bf16(ah, bh, acc[1], 0, 0, 0);
            acc[1] = __builtin_amdgcn_mfma_f32_16x16x32_bf16(ah, bl, acc[1], 0, 0, 0);
            acc[1] = __builtin_amdgcn_mfma_f32_16x16x32_bf16(al, bh, acc[1], 0, 0, 0);

            cvt8(*(const float4*)(bp2 + o), *(const float4*)(bp2 + o + 4), bh, bl);
            acc[2] = __builtin_amdgcn_mfma_f32_16x16x32_bf16(ah, bh, acc[2], 0, 0, 0);
            acc[2] = __builtin_amdgcn_mfma_f32_16x16x32_bf16(ah, bl, acc[2], 0, 0, 0);
            acc[2] = __builtin_amdgcn_mfma_f32_16x16x32_bf16(al, bh, acc[2], 0, 0, 0);
        }

        // C layout: col = lane&15 (f-row within tile), row = (lane>>4)*4 + reg (token)
        #pragma unroll
        for (int t = 0; t < 3; ++t) {
            #pragma unroll
            for (int r = 0; r < 4; ++r) {
                int m = (lane >> 4) * 4 + r;
                int j = t * 16 + (lane & 15);
                sc[(w * G + m) * JP + j] = acc[t][r];
            }
        }
    }
    __syncthreads();

    // ---------------- Phase 1.5: reduce partials + softmax -------------------
    {
        const int i   = tid >> 4;      // token 0..15
        const int sub = tid & 15;      // 16 threads per token (same wave, contiguous)

        float v[3];
        #pragma unroll
        for (int c = 0; c < 3; ++c) {
            int j = sub + c * 16;
            float s = sc[(0 * G + i) * JP + j] + sc[(1 * G + i) * JP + j]
                    + sc[(2 * G + i) * JP + j] + sc[(3 * G + i) * JP + j];
            bool valid = (j >= i) && (j <= i + 31) && (j <= jlim);
            v[c] = valid ? s : -1e9f;
        }
        float mx = fmaxf(v[0], fmaxf(v[1], v[2]));
        #pragma unroll
        for (int d = 1; d < 16; d <<= 1) mx = fmaxf(mx, __shfl_xor(mx, d, 16));

        float e[3];
        float sum = 0.f;
        #pragma unroll
        for (int c = 0; c < 3; ++c) { e[c] = __expf(v[c] - mx); sum += e[c]; }
        #pragma unroll
        for (int d = 1; d < 16; d <<= 1) sum += __shfl_xor(sum, d, 16);

        const bool any = (mx > -5e8f);
        const float inv = any ? (1.0f / sum) : 0.f;
        #pragma unroll
        for (int c = 0; c < 3; ++c) {
            int j = sub + c * 16;
            bool valid = (j >= i) && (j <= i + 31) && (j <= jlim);
            wm[i * JP + j] = valid ? e[c] * inv : 0.f;
        }
    }
    __syncthreads();

    // ---------------- Phase 2: PV in fp32 VALU, 4 tokens per wave ------------
    {
        const int i0   = w * 4;                 // wave's first token
        const int doff = lane * 4;              // 4 interleaved float4 chunks
        const int jhi  = min(min(i0 + 34, JW - 1), jlim);

        float4 a0[4] = {}, a1[4] = {}, a2[4] = {}, a3[4] = {};

        for (int j = i0; j <= jhi; ++j) {
            float w0 = wm[(i0 + 0) * JP + j];
            float w1 = wm[(i0 + 1) * JP + j];
            float w2 = wm[(i0 + 2) * JP + j];
            float w3 = wm[(i0 + 3) * JP + j];
            if (w0 + w1 + w2 + w3 != 0.f) {     // wave-uniform branch
                const float* fp = h + (size_t)(t0 + 1 + j) * D + doff;
                #pragma unroll
                for (int c = 0; c < 4; ++c) {
                    float4 f = *(const float4*)(fp + c * 256);
                    a0[c].x += w0 * f.x; a0[c].y += w0 * f.y; a0[c].z += w0 * f.z; a0[c].w += w0 * f.w;
                    a1[c].x += w1 * f.x; a1[c].y += w1 * f.y; a1[c].z += w1 * f.z; a1[c].w += w1 * f.w;
                    a2[c].x += w2 * f.x; a2[c].y += w2 * f.y; a2[c].z += w2 * f.z; a2[c].w += w2 * f.w;
                    a3[c].x += w3 * f.x; a3[c].y += w3 * f.y; a3[c].z += w3 * f.z; a3[c].w += w3 * f.w;
                }
            }
        }

        float* o0 = out + (size_t)(t0 + i0) * D + doff;
        #pragma unroll
        for (int c = 0; c < 4; ++c) *(float4*)(o0 + 0 * D + c * 256) = a0[c];
        #pragma unroll
        for (int c = 0; c < 4; ++c) *(float4*)(o0 + 1 * D + c * 256) = a1[c];
        #pragma unroll
        for (int c = 0; c < 4; ++c) *(float4*)(o0 + 2 * D + c * 256) = a2[c];
        #pragma unroll
        for (int c = 0; c < 4; ++c) *(float4*)(o0 + 3 * D + c * 256) = a3[c];
    }
}

extern "C" void kernel_launch(void* const* d_in, const int* in_sizes, int n_in,
                              void* d_out, int out_size, void* d_ws, size_t ws_size,
                              hipStream_t stream) {
    const float* h = (const float*)d_in[0];
    float* out = (float*)d_out;
    const int ntok = in_sizes[0] / D;        // 8192
    const int blocks = ntok / G;             // 512
    future_encoder_kernel<<<blocks, 256, 0, stream>>>(h, out);
}